// Round 1
// baseline (45.503 us; speedup 1.0000x reference)
//
#include <hip/hip_runtime.h>

#define TAU 0.25f
#define VTH 0.3f

// LIF spike recurrence over the last (time=8) axis.
// Each thread owns one neuron: 8 contiguous f32 in, 8 contiguous f32 out.
__global__ __launch_bounds__(256) void lif_kernel(const float* __restrict__ x,
                                                  float* __restrict__ out,
                                                  int n_neurons) {
    int idx = blockIdx.x * blockDim.x + threadIdx.x;
    int stride = gridDim.x * blockDim.x;
    for (int i = idx; i < n_neurons; i += stride) {
        const float4* xp = reinterpret_cast<const float4*>(x + (size_t)i * 8);
        float4 w0 = xp[0];
        float4 w1 = xp[1];
        float w[8] = {w0.x, w0.y, w0.z, w0.w, w1.x, w1.y, w1.z, w1.w};

        float u = 0.0f;
        float o = 0.0f;
        float r[8];
#pragma unroll
        for (int t = 0; t < 8; ++t) {
            // (1 - |o|) is exactly 0 or 1; TAU=0.25 multiply is exact.
            u = TAU * u * (1.0f - fabsf(o)) + w[t];
            float pos = (u > VTH) ? 1.0f : 0.0f;
            float neg = (u < -VTH) ? 1.0f : 0.0f;
            o = pos - neg;
            r[t] = o;
        }

        float4* op = reinterpret_cast<float4*>(out + (size_t)i * 8);
        op[0] = make_float4(r[0], r[1], r[2], r[3]);
        op[1] = make_float4(r[4], r[5], r[6], r[7]);
    }
}

extern "C" void kernel_launch(void* const* d_in, const int* in_sizes, int n_in,
                              void* d_out, int out_size, void* d_ws, size_t ws_size,
                              hipStream_t stream) {
    const float* x = (const float*)d_in[0];
    float* out = (float*)d_out;
    int n_neurons = in_sizes[0] / 8;  // 4,194,304

    const int block = 256;
    int grid = (n_neurons + block - 1) / block;
    if (grid > 2048) grid = 2048;  // grid-stride; 524,288 threads, 8 neurons each

    lif_kernel<<<grid, block, 0, stream>>>(x, out, n_neurons);
}